// Round 13
// baseline (105.286 us; speedup 1.0000x reference)
//
#include <hip/hip_runtime.h>
#include <cstdint>
#include <cstddef>

#define F_DIM 39
#define E_DIM 32
#define B_DIM 16384
#define ROWSTRIDE 1248              // 39*32 floats per b row
#define EPS_BN 1e-5f
#define EPS_G 1e-10f
#define NREP 8                      // m12 replica count (atomic spread)
#define GRID_F 208                  // <= 256 CUs: co-resident at 1 block/CU, guaranteed
#define UPB 6                       // units per block; 208*6 = 1248 = 39f x 32 chunks

typedef _Float16 f16x8 __attribute__((ext_vector_type(8)));
typedef float f32x16 __attribute__((ext_vector_type(16)));
union H8 { _Float16 h[8]; f16x8 v; uint32_t u[4]; };

// workspace (float units):
//   [0, 2048)      : m12f[rep][256]   -- memset 0 each launch, atomic-accumulated
//   [2048]         : barrier counter  -- memset 0 each launch (uint32)
//   [2052, 22020)  : Whp[f][16][32]   -- packed f16 pairs (uint32), builder-written
//   [22020, 23268) : bias[f][e]

// agent-scope arrive-and-wait barrier; release makes prior writes visible,
// acquire invalidates stale lines (per-XCD writeback L2 is why cg::grid.sync
// failed in r6/r7: control sync without cache maintenance).
__device__ __forceinline__ void gbar(uint32_t* cnt, uint32_t target) {
    __syncthreads();
    if (threadIdx.x == 0) {
        __hip_atomic_fetch_add(cnt, 1u, __ATOMIC_ACQ_REL, __HIP_MEMORY_SCOPE_AGENT);
        uint32_t v; long spins = 0;
        do {
            v = __hip_atomic_load(cnt, __ATOMIC_ACQUIRE, __HIP_MEMORY_SCOPE_AGENT);
        } while (v < target && ++spins < 100000000L);   // bounded: fail clean, never hang
    }
    __syncthreads();
}

__global__ __launch_bounds__(256) void k_fused(
    const float* __restrict__ emb,
    const float* __restrict__ w4, const float* __restrict__ w8,
    const float* __restrict__ w16, const float* __restrict__ w32,
    const float* __restrict__ gate, const float* __restrict__ noise,
    float* __restrict__ m12f, uint32_t* __restrict__ cnt,
    uint32_t* __restrict__ Whp, float* __restrict__ biasb,
    float* __restrict__ out)
{
    const int tid = threadIdx.x;
    const int wave = tid >> 6;
    const int l = tid & 63;
    const int g = l >> 5;
    const int c = l & 31;            // m-row within tile for A; n (=e) for B/D

    __shared__ float ldsY[4][128];
    __shared__ float ldsQ[4][128];
    __shared__ float ldsT[256];
    __shared__ float lg4[4];
    __shared__ float inv_s[4][32];
    __shared__ float mu_s[4][32];
    __shared__ float gate_s[4];

    const float* wt[4] = {w4, w8, w16, w32};

    // ================= phase 1: global Sy, Sy2 via MFMA Y-tiles =================
    float ysum[4] = {0.f, 0.f, 0.f, 0.f};
    float y2s[4] = {0.f, 0.f, 0.f, 0.f};

    for (int i = 0; i < UPB; ++i) {
        const int u = blockIdx.x * UPB + i;
        const int f = u >> 5;        // 32 chunks of 512 rows per field
        const int chunk = u & 31;

        // 5 non-zero B-fragments (k = 16*kq + 8*g + p; HW-validated r2-r5, r8-r12)
        H8 wf[5];
#pragma unroll
        for (int idx = 0; idx < 5; ++idx) {
            const int cc = (idx < 4) ? idx : 3;
            const int kq = (idx < 4) ? 0 : 1;
            const int d = 4 << cc;
            const float* w = wt[cc] + (size_t)f * d * E_DIM;
#pragma unroll
            for (int p = 0; p < 8; ++p) {
                const int k = 16 * kq + 8 * g + p;
                wf[idx].h[p] = (k < d) ? (_Float16)w[k * E_DIM + c] : (_Float16)0.f;
            }
        }

        const float* prow =
            emb + (size_t)(chunk * 512 + wave * 128 + c) * ROWSTRIDE + f * E_DIM;
#pragma unroll
        for (int t = 0; t < 4; ++t) {
            const float4* pa = reinterpret_cast<const float4*>(prow);
            const float4 v0 = pa[2 * g], v1 = pa[2 * g + 1];
            const float4 v2 = pa[4 + 2 * g], v3 = pa[4 + 2 * g + 1];
            H8 a0, a1;
            a0.h[0] = (_Float16)v0.x; a0.h[1] = (_Float16)v0.y;
            a0.h[2] = (_Float16)v0.z; a0.h[3] = (_Float16)v0.w;
            a0.h[4] = (_Float16)v1.x; a0.h[5] = (_Float16)v1.y;
            a0.h[6] = (_Float16)v1.z; a0.h[7] = (_Float16)v1.w;
            a1.h[0] = (_Float16)v2.x; a1.h[1] = (_Float16)v2.y;
            a1.h[2] = (_Float16)v2.z; a1.h[3] = (_Float16)v2.w;
            a1.h[4] = (_Float16)v3.x; a1.h[5] = (_Float16)v3.y;
            a1.h[6] = (_Float16)v3.z; a1.h[7] = (_Float16)v3.w;

#pragma unroll
            for (int cc = 0; cc < 4; ++cc) {
                f32x16 acc;
#pragma unroll
                for (int k = 0; k < 16; ++k) acc[k] = 0.f;
                acc = __builtin_amdgcn_mfma_f32_32x32x16_f16(a0.v, wf[cc].v, acc, 0, 0, 0);
                if (cc == 3)
                    acc = __builtin_amdgcn_mfma_f32_32x32x16_f16(a1.v, wf[4].v, acc, 0, 0, 0);
#pragma unroll
                for (int r = 0; r < 16; ++r) {
                    ysum[cc] += acc[r];
                    y2s[cc] = fmaf(acc[r], acc[r], y2s[cc]);
                }
            }
            prow += (size_t)32 * ROWSTRIDE;
        }
    }

#pragma unroll
    for (int cc = 0; cc < 4; ++cc) {
        ysum[cc] += __shfl_xor(ysum[cc], 32, 64);
        y2s[cc] += __shfl_xor(y2s[cc], 32, 64);
    }
    if (l < 32) {
#pragma unroll
        for (int cc = 0; cc < 4; ++cc) {
            ldsY[wave][cc * 32 + c] = ysum[cc];
            ldsQ[wave][cc * 32 + c] = y2s[cc];
        }
    }
    __syncthreads();
    if (tid < 128) {
        const int rep = blockIdx.x & (NREP - 1);
        unsafeAtomicAdd(&m12f[rep * 256 + tid],
                        ldsY[0][tid] + ldsY[1][tid] + ldsY[2][tid] + ldsY[3][tid]);
        unsafeAtomicAdd(&m12f[rep * 256 + 128 + tid],
                        ldsQ[0][tid] + ldsQ[1][tid] + ldsQ[2][tid] + ldsQ[3][tid]);
    }

    gbar(cnt, GRID_F);

    // ================= builder: blocks 0..38 -> global Whp/bias =================
    if (blockIdx.x < F_DIM) {
        const int f = blockIdx.x;
        {
            float s = 0.f;
#pragma unroll
            for (int r = 0; r < NREP; ++r) s += m12f[r * 256 + tid];
            ldsT[tid] = s;
        }
        if (tid < 4) {
            const float u = noise[f * 4 + tid];
            const float gg = -logf(-logf(u + EPS_G) + EPS_G);
            lg4[tid] = gate[f * 4 + tid] + gg;
        }
        __syncthreads();
        if (tid < 4) {
            const float mx = fmaxf(fmaxf(lg4[0], lg4[1]), fmaxf(lg4[2], lg4[3]));
            const float e0 = expf(lg4[0] - mx), e1 = expf(lg4[1] - mx);
            const float e2 = expf(lg4[2] - mx), e3 = expf(lg4[3] - mx);
            gate_s[tid] = 0.25f * expf(lg4[tid] - mx) / ((e0 + e1) + (e2 + e3));
        }
        if (tid >= 128 && tid < 256) {
            const int t2 = tid - 128;
            const int cc = t2 >> 5, e = t2 & 31;
            const float invBF = 1.0f / ((float)B_DIM * (float)F_DIM);
            const float mu = ldsT[t2] * invBF;
            const float ey2 = ldsT[128 + t2] * invBF;
            inv_s[cc][e] = rsqrtf(ey2 - mu * mu + EPS_BN);
            mu_s[cc][e] = mu;
        }
        __syncthreads();

        for (int idx = tid; idx < 512; idx += 256) {
            const int kp = idx >> 5;
            const int e = idx & 31;
            const int i0 = kp * 2;
            float w0 = 0.f, w1 = 0.f;
#pragma unroll
            for (int cc = 0; cc < 4; ++cc) {
                const int d = 4 << cc;
                if (i0 < d) {
                    const float* w = wt[cc];
                    const float gi = gate_s[cc] * inv_s[cc][e];
                    const size_t base = ((size_t)f * d + i0) * E_DIM + e;
                    w0 = fmaf(gi, w[base], w0);
                    w1 = fmaf(gi, w[base + E_DIM], w1);
                }
            }
            union { _Float16 h[2]; uint32_t uu; } ph;
            ph.h[0] = (_Float16)w0; ph.h[1] = (_Float16)w1;
            Whp[f * 512 + idx] = ph.uu;
        }
        if (tid < E_DIM) {
            float a = 0.f;
#pragma unroll
            for (int cc = 0; cc < 4; ++cc)
                a = fmaf(gate_s[cc], inv_s[cc][tid] * mu_s[cc][tid], a);
            biasb[f * E_DIM + tid] = a;
        }
    }

    gbar(cnt, 2 * GRID_F);

    // ============== phase 2: apply (emb re-read is L3-resident) ==============
    for (int i = 0; i < UPB; ++i) {
        const int u = blockIdx.x * UPB + i;
        const int f = u >> 5;
        const int chunk = u & 31;

        H8 wh[2];
#pragma unroll
        for (int q = 0; q < 2; ++q)
#pragma unroll
            for (int pp = 0; pp < 4; ++pp) {
                const int kp = 8 * q + 4 * g + pp;
                wh[q].u[pp] = Whp[f * 512 + kp * 32 + c];
            }
        const float be = biasb[f * 32 + c];

        const int wbase = chunk * 512 + wave * 128;
#pragma unroll
        for (int t = 0; t < 4; ++t) {
            const int b0 = wbase + t * 32;
            const float4* pa = reinterpret_cast<const float4*>(
                emb + (size_t)(b0 + c) * ROWSTRIDE + f * E_DIM + 8 * g);
            f32x16 acc;
#pragma unroll
            for (int k = 0; k < 16; ++k) acc[k] = 0.f;
#pragma unroll
            for (int q = 0; q < 2; ++q) {
                const float4 v0 = pa[4 * q];
                const float4 v1 = pa[4 * q + 1];
                H8 ah;
                ah.h[0] = (_Float16)v0.x; ah.h[1] = (_Float16)v0.y;
                ah.h[2] = (_Float16)v0.z; ah.h[3] = (_Float16)v0.w;
                ah.h[4] = (_Float16)v1.x; ah.h[5] = (_Float16)v1.y;
                ah.h[6] = (_Float16)v1.z; ah.h[7] = (_Float16)v1.w;
                acc = __builtin_amdgcn_mfma_f32_32x32x16_f16(ah.v, wh[q].v, acc, 0, 0, 0);
            }
            float* po = out + (size_t)b0 * ROWSTRIDE + f * E_DIM + c;
#pragma unroll
            for (int r = 0; r < 16; ++r) {
                const int mrow = (r & 3) + 8 * (r >> 2) + 4 * g;
                __builtin_nontemporal_store(acc[r] - be, po + (size_t)mrow * ROWSTRIDE);
            }
        }
    }
}

extern "C" void kernel_launch(void* const* d_in, const int* in_sizes, int n_in,
                              void* d_out, int out_size, void* d_ws, size_t ws_size,
                              hipStream_t stream) {
    const float* emb   = (const float*)d_in[0];
    const float* w4    = (const float*)d_in[1];
    const float* w8    = (const float*)d_in[2];
    const float* w16   = (const float*)d_in[3];
    const float* w32   = (const float*)d_in[4];
    const float* gate  = (const float*)d_in[5];
    const float* noise = (const float*)d_in[6];
    float* out = (float*)d_out;

    float* ws       = (float*)d_ws;
    float* m12f     = ws;                          // 2048 floats
    uint32_t* cnt   = (uint32_t*)(ws + 2048);      // 1 uint (pad to 2052)
    uint32_t* Whp   = (uint32_t*)(ws + 2052);      // 39*512
    float* biasb    = ws + 22020;                  // 39*32

    hipMemsetAsync(d_ws, 0, 2052 * sizeof(float), stream);
    k_fused<<<GRID_F, 256, 0, stream>>>(emb, w4, w8, w16, w32, gate, noise,
                                        m12f, cnt, Whp, biasb, out);
}

// Round 14
// 94.497 us; speedup vs baseline: 1.1142x; 1.1142x over previous
//
#include <hip/hip_runtime.h>
#include <cstdint>
#include <cstddef>

#define F_DIM 39
#define E_DIM 32
#define B_DIM 16384
#define ROWSTRIDE 1248              // 39*32 floats per b row
#define EPS_BN 1e-5f
#define EPS_G 1e-10f
#define NREP 8                      // m12 replica count (atomic spread)
#define GRID_F 208                  // <= 256 CUs: co-resident at 1 block/CU, guaranteed
#define UPB 6                       // units per block; 208*6 = 1248 = 39f x 32 chunks

typedef _Float16 f16x8 __attribute__((ext_vector_type(8)));
typedef float f32x16 __attribute__((ext_vector_type(16)));
union H8 { _Float16 h[8]; f16x8 v; uint32_t u[4]; };

// workspace (float units):
//   [0, 2048)      : m12f[rep][256]   -- memset 0 each launch, atomic-accumulated
//   [2048]         : barrier counter  -- memset 0 each launch (uint32)
//   [2052, 22020)  : Whp[f][16][32]   -- packed f16 pairs (uint32), builder-written
//   [22020, 23268) : bias[f][e]

// agent-scope arrive-and-wait barrier (r13-proven): release publishes writes,
// acquire invalidates stale per-XCD L2 lines. cg::grid.sync lacks this (r6/r7).
__device__ __forceinline__ void gbar(uint32_t* cnt, uint32_t target) {
    __syncthreads();
    if (threadIdx.x == 0) {
        __hip_atomic_fetch_add(cnt, 1u, __ATOMIC_ACQ_REL, __HIP_MEMORY_SCOPE_AGENT);
        uint32_t v; long spins = 0;
        do {
            v = __hip_atomic_load(cnt, __ATOMIC_ACQUIRE, __HIP_MEMORY_SCOPE_AGENT);
        } while (v < target && ++spins < 100000000L);   // bounded: fail clean, never hang
    }
    __syncthreads();
}

__global__ __launch_bounds__(1024) void k_fused(
    const float* __restrict__ emb,
    const float* __restrict__ w4, const float* __restrict__ w8,
    const float* __restrict__ w16, const float* __restrict__ w32,
    const float* __restrict__ gate, const float* __restrict__ noise,
    float* __restrict__ m12f, uint32_t* __restrict__ cnt,
    uint32_t* __restrict__ Whp, float* __restrict__ biasb,
    float* __restrict__ out)
{
    const int tid = threadIdx.x;
    const int wave = tid >> 6;       // 0..15
    const int l = tid & 63;
    const int g = l >> 5;
    const int c = l & 31;            // m-row within tile for A; n (=e) for B/D

    __shared__ float ldsY[16][128];
    __shared__ float ldsQ[16][128];
    __shared__ float ldsT[256];
    __shared__ float lg4[4];
    __shared__ float inv_s[4][32];
    __shared__ float mu_s[4][32];
    __shared__ float gate_s[4];

    const float* wt[4] = {w4, w8, w16, w32};

    // ================= phase 1: global Sy, Sy2 via MFMA Y-tiles =================
    // Each wave handles one 32-row tile per unit (16 waves x 32 = 512 rows/unit).
    float ysum[4] = {0.f, 0.f, 0.f, 0.f};
    float y2s[4] = {0.f, 0.f, 0.f, 0.f};

    for (int i = 0; i < UPB; ++i) {
        const int u = blockIdx.x * UPB + i;
        const int f = u >> 5;        // 32 chunks of 512 rows per field
        const int chunk = u & 31;

        // 5 non-zero B-fragments (k = 16*kq + 8*g + p; HW-validated r2-r5, r8-r13)
        H8 wf[5];
#pragma unroll
        for (int idx = 0; idx < 5; ++idx) {
            const int cc = (idx < 4) ? idx : 3;
            const int kq = (idx < 4) ? 0 : 1;
            const int d = 4 << cc;
            const float* w = wt[cc] + (size_t)f * d * E_DIM;
#pragma unroll
            for (int p = 0; p < 8; ++p) {
                const int k = 16 * kq + 8 * g + p;
                wf[idx].h[p] = (k < d) ? (_Float16)w[k * E_DIM + c] : (_Float16)0.f;
            }
        }

        const float4* pa = reinterpret_cast<const float4*>(
            emb + (size_t)(chunk * 512 + wave * 32 + c) * ROWSTRIDE + f * E_DIM);
        const float4 v0 = pa[2 * g], v1 = pa[2 * g + 1];
        const float4 v2 = pa[4 + 2 * g], v3 = pa[4 + 2 * g + 1];
        H8 a0, a1;
        a0.h[0] = (_Float16)v0.x; a0.h[1] = (_Float16)v0.y;
        a0.h[2] = (_Float16)v0.z; a0.h[3] = (_Float16)v0.w;
        a0.h[4] = (_Float16)v1.x; a0.h[5] = (_Float16)v1.y;
        a0.h[6] = (_Float16)v1.z; a0.h[7] = (_Float16)v1.w;
        a1.h[0] = (_Float16)v2.x; a1.h[1] = (_Float16)v2.y;
        a1.h[2] = (_Float16)v2.z; a1.h[3] = (_Float16)v2.w;
        a1.h[4] = (_Float16)v3.x; a1.h[5] = (_Float16)v3.y;
        a1.h[6] = (_Float16)v3.z; a1.h[7] = (_Float16)v3.w;

#pragma unroll
        for (int cc = 0; cc < 4; ++cc) {
            f32x16 acc;
#pragma unroll
            for (int k = 0; k < 16; ++k) acc[k] = 0.f;
            acc = __builtin_amdgcn_mfma_f32_32x32x16_f16(a0.v, wf[cc].v, acc, 0, 0, 0);
            if (cc == 3)
                acc = __builtin_amdgcn_mfma_f32_32x32x16_f16(a1.v, wf[4].v, acc, 0, 0, 0);
            // column sums only: D col = c for this lane; row mapping irrelevant
#pragma unroll
            for (int r = 0; r < 16; ++r) {
                ysum[cc] += acc[r];
                y2s[cc] = fmaf(acc[r], acc[r], y2s[cc]);
            }
        }
    }

#pragma unroll
    for (int cc = 0; cc < 4; ++cc) {
        ysum[cc] += __shfl_xor(ysum[cc], 32, 64);
        y2s[cc] += __shfl_xor(y2s[cc], 32, 64);
    }
    if (l < 32) {
#pragma unroll
        for (int cc = 0; cc < 4; ++cc) {
            ldsY[wave][cc * 32 + c] = ysum[cc];
            ldsQ[wave][cc * 32 + c] = y2s[cc];
        }
    }
    __syncthreads();
    if (tid < 128) {
        float sy = 0.f, sq = 0.f;
#pragma unroll
        for (int w = 0; w < 16; ++w) { sy += ldsY[w][tid]; sq += ldsQ[w][tid]; }
        const int rep = blockIdx.x & (NREP - 1);
        unsafeAtomicAdd(&m12f[rep * 256 + tid], sy);
        unsafeAtomicAdd(&m12f[rep * 256 + 128 + tid], sq);
    }

    gbar(cnt, GRID_F);

    // ================= builder: blocks 0..38 -> global Whp/bias =================
    if (blockIdx.x < F_DIM) {
        const int f = blockIdx.x;
        if (tid < 256) {
            float s = 0.f;
#pragma unroll
            for (int r = 0; r < NREP; ++r) s += m12f[r * 256 + tid];
            ldsT[tid] = s;
        }
        if (tid < 4) {
            const float u = noise[f * 4 + tid];
            const float gg = -logf(-logf(u + EPS_G) + EPS_G);
            lg4[tid] = gate[f * 4 + tid] + gg;
        }
        __syncthreads();
        if (tid < 4) {
            const float mx = fmaxf(fmaxf(lg4[0], lg4[1]), fmaxf(lg4[2], lg4[3]));
            const float e0 = expf(lg4[0] - mx), e1 = expf(lg4[1] - mx);
            const float e2 = expf(lg4[2] - mx), e3 = expf(lg4[3] - mx);
            gate_s[tid] = 0.25f * expf(lg4[tid] - mx) / ((e0 + e1) + (e2 + e3));
        }
        if (tid >= 128 && tid < 256) {
            const int t2 = tid - 128;
            const int cc = t2 >> 5, e = t2 & 31;
            const float invBF = 1.0f / ((float)B_DIM * (float)F_DIM);
            const float mu = ldsT[t2] * invBF;
            const float ey2 = ldsT[128 + t2] * invBF;
            inv_s[cc][e] = rsqrtf(ey2 - mu * mu + EPS_BN);
            mu_s[cc][e] = mu;
        }
        __syncthreads();

        if (tid < 512) {
            const int kp = tid >> 5;
            const int e = tid & 31;
            const int i0 = kp * 2;
            float w0 = 0.f, w1 = 0.f;
#pragma unroll
            for (int cc = 0; cc < 4; ++cc) {
                const int d = 4 << cc;
                if (i0 < d) {
                    const float* w = wt[cc];
                    const float gi = gate_s[cc] * inv_s[cc][e];
                    const size_t base = ((size_t)f * d + i0) * E_DIM + e;
                    w0 = fmaf(gi, w[base], w0);
                    w1 = fmaf(gi, w[base + E_DIM], w1);
                }
            }
            union { _Float16 h[2]; uint32_t uu; } ph;
            ph.h[0] = (_Float16)w0; ph.h[1] = (_Float16)w1;
            Whp[f * 512 + tid] = ph.uu;
        }
        if (tid < E_DIM) {
            float a = 0.f;
#pragma unroll
            for (int cc = 0; cc < 4; ++cc)
                a = fmaf(gate_s[cc], inv_s[cc][tid] * mu_s[cc][tid], a);
            biasb[f * E_DIM + tid] = a;
        }
    }

    gbar(cnt, 2 * GRID_F);

    // ============== phase 2: apply (emb re-read is L3-resident) ==============
    for (int i = 0; i < UPB; ++i) {
        const int u = blockIdx.x * UPB + i;
        const int f = u >> 5;
        const int chunk = u & 31;

        H8 wh[2];
#pragma unroll
        for (int q = 0; q < 2; ++q)
#pragma unroll
            for (int pp = 0; pp < 4; ++pp) {
                const int kp = 8 * q + 4 * g + pp;
                wh[q].u[pp] = Whp[f * 512 + kp * 32 + c];
            }
        const float be = biasb[f * 32 + c];

        const int b0 = chunk * 512 + wave * 32;
        const float4* pa = reinterpret_cast<const float4*>(
            emb + (size_t)(b0 + c) * ROWSTRIDE + f * E_DIM + 8 * g);
        f32x16 acc;
#pragma unroll
        for (int k = 0; k < 16; ++k) acc[k] = 0.f;
#pragma unroll
        for (int q = 0; q < 2; ++q) {
            const float4 v0 = pa[4 * q];
            const float4 v1 = pa[4 * q + 1];
            H8 ah;
            ah.h[0] = (_Float16)v0.x; ah.h[1] = (_Float16)v0.y;
            ah.h[2] = (_Float16)v0.z; ah.h[3] = (_Float16)v0.w;
            ah.h[4] = (_Float16)v1.x; ah.h[5] = (_Float16)v1.y;
            ah.h[6] = (_Float16)v1.z; ah.h[7] = (_Float16)v1.w;
            acc = __builtin_amdgcn_mfma_f32_32x32x16_f16(ah.v, wh[q].v, acc, 0, 0, 0);
        }
        float* po = out + (size_t)b0 * ROWSTRIDE + f * E_DIM + c;
#pragma unroll
        for (int r = 0; r < 16; ++r) {
            const int mrow = (r & 3) + 8 * (r >> 2) + 4 * g;
            __builtin_nontemporal_store(acc[r] - be, po + (size_t)mrow * ROWSTRIDE);
        }
    }
}

extern "C" void kernel_launch(void* const* d_in, const int* in_sizes, int n_in,
                              void* d_out, int out_size, void* d_ws, size_t ws_size,
                              hipStream_t stream) {
    const float* emb   = (const float*)d_in[0];
    const float* w4    = (const float*)d_in[1];
    const float* w8    = (const float*)d_in[2];
    const float* w16   = (const float*)d_in[3];
    const float* w32   = (const float*)d_in[4];
    const float* gate  = (const float*)d_in[5];
    const float* noise = (const float*)d_in[6];
    float* out = (float*)d_out;

    float* ws       = (float*)d_ws;
    float* m12f     = ws;                          // 2048 floats
    uint32_t* cnt   = (uint32_t*)(ws + 2048);      // 1 uint (pad to 2052)
    uint32_t* Whp   = (uint32_t*)(ws + 2052);      // 39*512
    float* biasb    = ws + 22020;                  // 39*32

    hipMemsetAsync(d_ws, 0, 2052 * sizeof(float), stream);
    k_fused<<<GRID_F, 1024, 0, stream>>>(emb, w4, w8, w16, w32, gate, noise,
                                         m12f, cnt, Whp, biasb, out);
}

// Round 15
// 55.416 us; speedup vs baseline: 1.8999x; 1.7052x over previous
//
#include <hip/hip_runtime.h>
#include <cstdint>
#include <cstddef>

#define F_DIM 39
#define E_DIM 32
#define B_DIM 16384
#define ROWSTRIDE 1248              // 39*32 floats per b row
#define EPS_BN 1e-5f
#define EPS_G 1e-10f
#define NREP 8                      // m12 replica count (atomic spread)

typedef _Float16 f16x8 __attribute__((ext_vector_type(8)));
typedef float f32x16 __attribute__((ext_vector_type(16)));
union H8 { _Float16 h[8]; f16x8 v; uint32_t u[4]; };

// workspace (float units):
//   [0, 2048) : m12f[rep][256]  ({Sy(128), Sy2(128)} per replica) -- memset to 0
//               each launch, then atomically accumulated by k_stats.

// ---- pass 1: global Sy, Sy2 of candidate outputs via MFMA Y-tiles + atomics ----
#define S_CHUNKS 32
#define S_RPB 512                    // rows/block; 128/wave; 4 tiles of 32

__global__ __launch_bounds__(256) void k_stats(const float* __restrict__ emb,
    const float* __restrict__ w4, const float* __restrict__ w8,
    const float* __restrict__ w16, const float* __restrict__ w32,
    float* __restrict__ m12f) {
    const int f = blockIdx.y;
    const int chunk = blockIdx.x;
    const int tid = threadIdx.x;
    const int wave = tid >> 6;
    const int l = tid & 63;
    const int g = l >> 5;
    const int c = l & 31;            // column: m-row for A, n (=e) for B/D

    // 5 non-zero B-fragments: idx -> (cc,kq): 0:(0,0) 1:(1,0) 2:(2,0) 3:(3,0) 4:(3,1)
    // k-slot p of half g holds k = 16*kq + 8*g + p (HW-validated rounds 2-5, 8-14).
    H8 wf[5];
    {
        const float* wt[4] = {w4, w8, w16, w32};
#pragma unroll
        for (int idx = 0; idx < 5; ++idx) {
            const int cc = (idx < 4) ? idx : 3;
            const int kq = (idx < 4) ? 0 : 1;
            const int d = 4 << cc;
            const float* w = wt[cc] + (size_t)f * d * E_DIM;
#pragma unroll
            for (int p = 0; p < 8; ++p) {
                const int k = 16 * kq + 8 * g + p;
                wf[idx].h[p] = (k < d) ? (_Float16)w[k * E_DIM + c] : (_Float16)0.f;
            }
        }
    }

    float ysum[4] = {0.f, 0.f, 0.f, 0.f};
    float y2s[4] = {0.f, 0.f, 0.f, 0.f};
    const float* prow = emb + (size_t)(chunk * S_RPB + wave * 128 + c) * ROWSTRIDE + f * E_DIM;

#pragma unroll
    for (int t = 0; t < 4; ++t) {
        const float4* pa = reinterpret_cast<const float4*>(prow);
        const float4 v0 = pa[2 * g], v1 = pa[2 * g + 1];
        const float4 v2 = pa[4 + 2 * g], v3 = pa[4 + 2 * g + 1];
        H8 a0, a1;
        a0.h[0] = (_Float16)v0.x; a0.h[1] = (_Float16)v0.y;
        a0.h[2] = (_Float16)v0.z; a0.h[3] = (_Float16)v0.w;
        a0.h[4] = (_Float16)v1.x; a0.h[5] = (_Float16)v1.y;
        a0.h[6] = (_Float16)v1.z; a0.h[7] = (_Float16)v1.w;
        a1.h[0] = (_Float16)v2.x; a1.h[1] = (_Float16)v2.y;
        a1.h[2] = (_Float16)v2.z; a1.h[3] = (_Float16)v2.w;
        a1.h[4] = (_Float16)v3.x; a1.h[5] = (_Float16)v3.y;
        a1.h[6] = (_Float16)v3.z; a1.h[7] = (_Float16)v3.w;

#pragma unroll
        for (int cc = 0; cc < 4; ++cc) {
            f32x16 acc;
#pragma unroll
            for (int i = 0; i < 16; ++i) acc[i] = 0.f;
            acc = __builtin_amdgcn_mfma_f32_32x32x16_f16(a0.v, wf[cc].v, acc, 0, 0, 0);
            if (cc == 3)
                acc = __builtin_amdgcn_mfma_f32_32x32x16_f16(a1.v, wf[4].v, acc, 0, 0, 0);
            // column sums only: D col = c for this lane; row mapping irrelevant
#pragma unroll
            for (int r = 0; r < 16; ++r) {
                ysum[cc] += acc[r];
                y2s[cc] = fmaf(acc[r], acc[r], y2s[cc]);
            }
        }
        prow += (size_t)32 * ROWSTRIDE;
    }

#pragma unroll
    for (int cc = 0; cc < 4; ++cc) {
        ysum[cc] += __shfl_xor(ysum[cc], 32, 64);
        y2s[cc] += __shfl_xor(y2s[cc], 32, 64);
    }
    __shared__ float ldsY[4][128];
    __shared__ float ldsQ[4][128];
    if (l < 32) {
#pragma unroll
        for (int cc = 0; cc < 4; ++cc) {
            ldsY[wave][cc * 32 + c] = ysum[cc];
            ldsQ[wave][cc * 32 + c] = y2s[cc];
        }
    }
    __syncthreads();
    if (tid < 128) {
        const int rep = chunk & (NREP - 1);
        unsafeAtomicAdd(&m12f[rep * 256 + tid],
                        ldsY[0][tid] + ldsY[1][tid] + ldsY[2][tid] + ldsY[3][tid]);
        unsafeAtomicAdd(&m12f[rep * 256 + 128 + tid],
                        ldsQ[0][tid] + ldsQ[1][tid] + ldsQ[2][tid] + ldsQ[3][tid]);
    }
}

// ---- pass 2 (fused): replica-sum -> BN stats -> gates -> LDS Weff -> apply ----
// 512 threads, pure-f16 MFMA (error budget: +~3e-3 vs hi/lo split, 2.3x under threshold)
#define A_CHUNKS 16
#define A_RPB (B_DIM / A_CHUNKS)     // 1024 rows/block; 8 waves x 128 rows (4 tiles)

__global__ __launch_bounds__(512) void k_apply(const float* __restrict__ emb,
    const float* __restrict__ m12f,
    const float* __restrict__ gate, const float* __restrict__ noise,
    const float* __restrict__ w4, const float* __restrict__ w8,
    const float* __restrict__ w16, const float* __restrict__ w32,
    float* __restrict__ out) {
    const int f = blockIdx.y;
    const int tid = threadIdx.x;
    const int wave = tid >> 6;
    const int l = tid & 63;
    const int g = l >> 5;
    const int c = l & 31;

    __shared__ float ldsT[256];
    __shared__ float lg4[4];
    __shared__ float inv_s[4][32];
    __shared__ float mu_s[4][32];
    __shared__ float gate_s[4];
    __shared__ uint32_t ldsWhp[512];
    __shared__ float ldsBias[32];

    // ---- build prologue ----
    if (tid < 256) {
        float s0 = 0.f, s1 = 0.f, s2 = 0.f, s3 = 0.f;
#pragma unroll
        for (int r = 0; r < NREP; r += 4) {
            s0 += m12f[(r + 0) * 256 + tid];
            s1 += m12f[(r + 1) * 256 + tid];
            s2 += m12f[(r + 2) * 256 + tid];
            s3 += m12f[(r + 3) * 256 + tid];
        }
        ldsT[tid] = (s0 + s1) + (s2 + s3);
    }
    if (tid < 4) {
        const float u = noise[f * 4 + tid];
        const float gg = -logf(-logf(u + EPS_G) + EPS_G);
        lg4[tid] = gate[f * 4 + tid] + gg;
    }
    __syncthreads();
    if (tid < 4) {
        const float mx = fmaxf(fmaxf(lg4[0], lg4[1]), fmaxf(lg4[2], lg4[3]));
        const float e0 = expf(lg4[0] - mx), e1 = expf(lg4[1] - mx);
        const float e2 = expf(lg4[2] - mx), e3 = expf(lg4[3] - mx);
        gate_s[tid] = 0.25f * expf(lg4[tid] - mx) / ((e0 + e1) + (e2 + e3));
    }
    if (tid >= 128 && tid < 256) {
        const int t2 = tid - 128;
        const int cc = t2 >> 5, e = t2 & 31;
        const float invBF = 1.0f / ((float)B_DIM * (float)F_DIM);
        const float mu = ldsT[t2] * invBF;
        const float ey2 = ldsT[128 + t2] * invBF;
        inv_s[cc][e] = rsqrtf(ey2 - mu * mu + EPS_BN);
        mu_s[cc][e] = mu;
    }
    __syncthreads();

    {   // one shot: 512 threads build 512 packed f16 pairs (hi only)
        const int kp = tid >> 5;
        const int e = tid & 31;
        const int i0 = kp * 2;
        float w0 = 0.f, w1 = 0.f;
#pragma unroll
        for (int cc = 0; cc < 4; ++cc) {
            const int d = 4 << cc;
            if (i0 < d) {
                const float* w = (cc == 0) ? w4 : (cc == 1) ? w8 : (cc == 2) ? w16 : w32;
                const float gi = gate_s[cc] * inv_s[cc][e];
                const size_t base = ((size_t)f * d + i0) * E_DIM + e;
                w0 = fmaf(gi, w[base], w0);
                w1 = fmaf(gi, w[base + E_DIM], w1);
            }
        }
        union { _Float16 h[2]; uint32_t uu; } ph;
        ph.h[0] = (_Float16)w0; ph.h[1] = (_Float16)w1;
        ldsWhp[tid] = ph.uu;
    }
    if (tid < E_DIM) {
        float a = 0.f;
#pragma unroll
        for (int cc = 0; cc < 4; ++cc)
            a = fmaf(gate_s[cc], inv_s[cc][tid] * mu_s[cc][tid], a);
        ldsBias[tid] = a;
    }
    __syncthreads();

    // ---- apply main loop (pure f16: 2 MFMA per tile) ----
    H8 wh[2];
#pragma unroll
    for (int q = 0; q < 2; ++q)
#pragma unroll
        for (int pp = 0; pp < 4; ++pp) {
            const int kp = 8 * q + 4 * g + pp;
            wh[q].u[pp] = ldsWhp[kp * 32 + c];
        }
    const float be = ldsBias[c];

    const int wbase = blockIdx.x * A_RPB + wave * 128;
#pragma unroll
    for (int t = 0; t < 4; ++t) {
        const int b0 = wbase + t * 32;
        const float4* pa = reinterpret_cast<const float4*>(
            emb + (size_t)(b0 + c) * ROWSTRIDE + f * E_DIM + 8 * g);
        f32x16 acc;
#pragma unroll
        for (int i = 0; i < 16; ++i) acc[i] = 0.f;
#pragma unroll
        for (int q = 0; q < 2; ++q) {
            const float4 v0 = pa[4 * q];
            const float4 v1 = pa[4 * q + 1];
            H8 ah;
            ah.h[0] = (_Float16)v0.x; ah.h[1] = (_Float16)v0.y;
            ah.h[2] = (_Float16)v0.z; ah.h[3] = (_Float16)v0.w;
            ah.h[4] = (_Float16)v1.x; ah.h[5] = (_Float16)v1.y;
            ah.h[6] = (_Float16)v1.z; ah.h[7] = (_Float16)v1.w;
            acc = __builtin_amdgcn_mfma_f32_32x32x16_f16(ah.v, wh[q].v, acc, 0, 0, 0);
        }
        float* po = out + (size_t)b0 * ROWSTRIDE + f * E_DIM + c;
#pragma unroll
        for (int r = 0; r < 16; ++r) {
            const int mrow = (r & 3) + 8 * (r >> 2) + 4 * g;
            __builtin_nontemporal_store(acc[r] - be, po + (size_t)mrow * ROWSTRIDE);
        }
    }
}

extern "C" void kernel_launch(void* const* d_in, const int* in_sizes, int n_in,
                              void* d_out, int out_size, void* d_ws, size_t ws_size,
                              hipStream_t stream) {
    const float* emb   = (const float*)d_in[0];
    const float* w4    = (const float*)d_in[1];
    const float* w8    = (const float*)d_in[2];
    const float* w16   = (const float*)d_in[3];
    const float* w32   = (const float*)d_in[4];
    const float* gate  = (const float*)d_in[5];
    const float* noise = (const float*)d_in[6];
    float* out = (float*)d_out;

    float* m12f = (float*)d_ws;       // NREP*256 floats

    hipMemsetAsync(m12f, 0, NREP * 256 * sizeof(float), stream);
    k_stats<<<dim3(S_CHUNKS, F_DIM), 256, 0, stream>>>(emb, w4, w8, w16, w32, m12f);
    k_apply<<<dim3(A_CHUNKS, F_DIM), 512, 0, stream>>>(emb, m12f, gate, noise,
                                                       w4, w8, w16, w32, out);
}